// Round 3
// baseline (1235.413 us; speedup 1.0000x reference)
//
#include <hip/hip_runtime.h>
#include <math.h>

#define D_MODEL 4096
#define N_EXP   64
#define NTHR    256
#define KC      16            // k per chunk iteration
#define KQ      1024          // k per wave (quarter of D_MODEL)
#define NCHUNK  (KQ / KC)     // 64
#define RPAD    68            // padded row (floats) for reduce buffer

// Transpose W[64][4096] -> Wt[4096][64] (into d_ws). Runs every launch
// (deterministic, no cross-call state).
__global__ __launch_bounds__(256)
void wt_kernel(const float* __restrict__ W, float* __restrict__ Wt) {
    __shared__ float t[64][65];
    const int tid = threadIdx.x;
    const int k0  = blockIdx.x * 64;
    #pragma unroll
    for (int r = 0; r < 16; ++r) {
        const int e  = r * 4 + (tid >> 6);
        const int kk = tid & 63;
        t[kk][e] = W[(size_t)e * D_MODEL + k0 + kk];   // coalesced read
    }
    __syncthreads();
    #pragma unroll
    for (int r = 0; r < 16; ++r) {
        const int kk = r * 4 + (tid >> 6);
        const int e  = tid & 63;
        Wt[(size_t)(k0 + kk) * N_EXP + e] = t[kk][e];  // coalesced write
    }
}

// lane = token (64 tokens/block), wave = k-quarter. All W reads are
// wave-uniform -> scalar loads; FMA is v_fmac(v_acc, s_w, v_x). No LDS
// in the hot loop.
__global__ __launch_bounds__(NTHR, 2)
void router_kernel(const float* __restrict__ x, const float* __restrict__ Wt,
                   float* __restrict__ out, int ntok) {
    __shared__ float red[4 * 64 * RPAD];

    const int tid  = threadIdx.x;
    const int w    = tid >> 6;     // k-quarter
    const int lane = tid & 63;     // token within block
    const int tok0 = blockIdx.x * 64;

    const float* xrow = x + (size_t)(tok0 + lane) * D_MODEL + w * KQ;
    const float* wq   = Wt + (size_t)w * KQ * N_EXP;

    float  acc[N_EXP];
    double dacc[N_EXP];
    #pragma unroll
    for (int e = 0; e < N_EXP; ++e) { acc[e] = 0.0f; dacc[e] = 0.0; }

    for (int c = 0; c < NCHUNK; ++c) {
        float4 xv[4];
        #pragma unroll
        for (int q = 0; q < 4; ++q)
            xv[q] = *(const float4*)(xrow + c * KC + q * 4);
        const float* wr = wq + (size_t)c * KC * N_EXP;
        #pragma unroll
        for (int kk = 0; kk < KC; ++kk) {
            const float xvk = ((const float*)xv)[kk];          // static idx
            const float4* w4 = (const float4*)(wr + kk * N_EXP); // uniform addr
            #pragma unroll
            for (int e4 = 0; e4 < 16; ++e4) {
                const float4 wv = w4[e4];
                acc[e4 * 4 + 0] = fmaf(wv.x, xvk, acc[e4 * 4 + 0]);
                acc[e4 * 4 + 1] = fmaf(wv.y, xvk, acc[e4 * 4 + 1]);
                acc[e4 * 4 + 2] = fmaf(wv.z, xvk, acc[e4 * 4 + 2]);
                acc[e4 * 4 + 3] = fmaf(wv.w, xvk, acc[e4 * 4 + 3]);
            }
        }
        // fold fp32 chunk into fp64 master every 64 k (chunk err ~2e-8)
        if ((c & 3) == 3) {
            #pragma unroll
            for (int e = 0; e < N_EXP; ++e) { dacc[e] += (double)acc[e]; acc[e] = 0.0f; }
        }
    }

    // write per-wave fp32 partials (each ~3e-8 accurate)
    #pragma unroll
    for (int e4 = 0; e4 < 16; ++e4) {
        float4 v;
        v.x = (float)dacc[e4 * 4 + 0];
        v.y = (float)dacc[e4 * 4 + 1];
        v.z = (float)dacc[e4 * 4 + 2];
        v.w = (float)dacc[e4 * 4 + 3];
        *(float4*)&red[(size_t)(w * 64 + lane) * RPAD + e4 * 4] = v;
    }
    __syncthreads();

    // reduce + top-2: 4 threads per token (consecutive lanes), 16 experts each
    const int t   = tid >> 2;
    const int sub = tid & 3;

    float v1 = -3.0e38f, v2 = -3.0e38f;
    int   i1 = 1 << 30,  i2 = 1 << 30;
    #pragma unroll
    for (int e4 = 0; e4 < 4; ++e4) {
        const int eb = sub * 16 + e4 * 4;
        float4 s0 = *(const float4*)&red[(size_t)(0 * 64 + t) * RPAD + eb];
        float4 s1 = *(const float4*)&red[(size_t)(1 * 64 + t) * RPAD + eb];
        float4 s2 = *(const float4*)&red[(size_t)(2 * 64 + t) * RPAD + eb];
        float4 s3 = *(const float4*)&red[(size_t)(3 * 64 + t) * RPAD + eb];
        float sv[4];
        sv[0] = (float)((double)s0.x + (double)s1.x + (double)s2.x + (double)s3.x);
        sv[1] = (float)((double)s0.y + (double)s1.y + (double)s2.y + (double)s3.y);
        sv[2] = (float)((double)s0.z + (double)s1.z + (double)s2.z + (double)s3.z);
        sv[3] = (float)((double)s0.w + (double)s1.w + (double)s2.w + (double)s3.w);
        #pragma unroll
        for (int j = 0; j < 4; ++j) {
            const float v  = sv[j];
            const int   id = eb + j;
            if (v > v1 || (v == v1 && id < i1)) {
                v2 = v1; i2 = i1; v1 = v; i1 = id;
            } else if (v > v2 || (v == v2 && id < i2)) {
                v2 = v; i2 = id;
            }
        }
    }
    // merge across the 4 sub-threads (same wave, xor 1,2 stay in group)
    #pragma unroll
    for (int m = 1; m < 4; m <<= 1) {
        float ov1 = __shfl_xor(v1, m, 64);
        int   oi1 = __shfl_xor(i1, m, 64);
        float ov2 = __shfl_xor(v2, m, 64);
        int   oi2 = __shfl_xor(i2, m, 64);
        bool ofirst = (ov1 > v1) || (ov1 == v1 && oi1 < i1);
        if (ofirst) {
            bool s2 = (ov2 > v1) || (ov2 == v1 && oi2 < i1);
            v2 = s2 ? ov2 : v1;  i2 = s2 ? oi2 : i1;
            v1 = ov1;            i1 = oi1;
        } else {
            bool s2 = (ov1 > v2) || (ov1 == v2 && oi1 < i2);
            v2 = s2 ? ov1 : v2;  i2 = s2 ? oi1 : i2;
        }
    }

    if (sub == 0) {
        const int tok = tok0 + t;
        float e = expf(v2 - v1);     // <= 1
        float d = 1.0f + e;
        out[2 * tok + 0] = 1.0f / d;
        out[2 * tok + 1] = e / d;
        float* out_e = out + (size_t)2 * ntok;
        out_e[2 * tok + 0] = (float)i1;
        out_e[2 * tok + 1] = (float)i2;
    }
}

extern "C" void kernel_launch(void* const* d_in, const int* in_sizes, int n_in,
                              void* d_out, int out_size, void* d_ws, size_t ws_size,
                              hipStream_t stream) {
    const float* x = (const float*)d_in[0];
    const float* W = (const float*)d_in[1];
    float* out = (float*)d_out;
    float* Wt  = (float*)d_ws;                 // 4096*64*4 = 1 MB scratch
    const int ntok = in_sizes[0] / D_MODEL;    // 32768

    wt_kernel<<<dim3(D_MODEL / 64), dim3(256), 0, stream>>>(W, Wt);
    router_kernel<<<dim3(ntok / 64), dim3(NTHR), 0, stream>>>(x, Wt, out, ntok);
}

// Round 4
// 215.617 us; speedup vs baseline: 5.7297x; 5.7297x over previous
//
#include <hip/hip_runtime.h>
#include <math.h>

#define D_MODEL 4096
#define N_EXP   64

typedef _Float16 half8 __attribute__((ext_vector_type(8)));
typedef float    f32x4 __attribute__((ext_vector_type(4)));

// ---------------------------------------------------------------------------
// Prep: W[64][4096] fp32 -> fragment-ordered fp16 hi/lo arrays (in d_ws).
// Ws = W*64 (2^6, keeps values ~N(0,1)); hi = fp16(Ws); lo = fp16((Ws-hi)*4096)
// (residual exact by Sterbenz; *2^12 keeps lo in fp16 normal range).
// Fragment order: [kstep 0..127][nt 0..3][lane 0..63][j 0..7], so a wave's
// B-frag load is one contiguous 1 KB block: element (kstep,nt,lane,j) at
// linear index ((kstep*4+nt)*64+lane)*8+j, with expert e = nt*16+(lane&15),
// k = kstep*32+(lane>>4)*8+j.  A uses the SAME (lane>>4)*8+j k-convention, so
// any HW k-permutation cancels (dot is permutation-invariant in k).
// ---------------------------------------------------------------------------
__global__ __launch_bounds__(256)
void wprep_kernel(const float* __restrict__ W,
                  _Float16* __restrict__ whf, _Float16* __restrict__ wlf) {
    const int gid   = blockIdx.x * 256 + threadIdx.x;   // 0..32767
    const int lane  = gid & 63;
    const int ntk   = gid >> 6;
    const int nt    = ntk & 3;
    const int kstep = ntk >> 2;
    const int e  = nt * 16 + (lane & 15);
    const int k0 = kstep * 32 + (lane >> 4) * 8;

    const float* src = W + (size_t)e * D_MODEL + k0;
    float4 w0 = *(const float4*)(src);
    float4 w1 = *(const float4*)(src + 4);
    float wv[8] = {w0.x, w0.y, w0.z, w0.w, w1.x, w1.y, w1.z, w1.w};

    half8 hh, ll;
    #pragma unroll
    for (int j = 0; j < 8; ++j) {
        float ws = wv[j] * 64.0f;
        _Float16 h = (_Float16)ws;
        hh[j] = h;
        ll[j] = (_Float16)((ws - (float)h) * 4096.0f);
    }
    *(half8*)(whf + (size_t)gid * 8) = hh;
    *(half8*)(wlf + (size_t)gid * 8) = ll;
}

// ---------------------------------------------------------------------------
// Main: block = 32 tokens, 4 waves. Wave w: token strip (w&1)*16, K-half
// (w>>1)*64 ksteps. A loaded per-lane straight from global in fragment
// layout (row = l&15, k = kstep*32+(l>>4)*8, 32B/lane — coalesced, read
// once). B streamed from L2-resident frag arrays. No LDS in hot loop.
// ---------------------------------------------------------------------------
__device__ __forceinline__ void do_kstep(const float4 a0, const float4 a1,
                                         const _Float16* __restrict__ whf,
                                         const _Float16* __restrict__ wlf,
                                         int ks, int l,
                                         f32x4 acc_hh[4], f32x4 acc_c[4]) {
    // B loads first (L2 latency hides under the A-convert VALU below)
    half8 bh[4], bl[4];
    const size_t boff = (size_t)(ks * 4) * 512 + (size_t)l * 8;
    #pragma unroll
    for (int nt = 0; nt < 4; ++nt) {
        bh[nt] = *(const half8*)(whf + boff + nt * 512);
        bl[nt] = *(const half8*)(wlf + boff + nt * 512);
    }
    // A fp32 -> fp16 hi/lo (residual exact; *2^12 keeps lo normal)
    float av[8] = {a0.x, a0.y, a0.z, a0.w, a1.x, a1.y, a1.z, a1.w};
    half8 ah, al;
    #pragma unroll
    for (int j = 0; j < 8; ++j) {
        _Float16 h = (_Float16)av[j];
        ah[j] = h;
        al[j] = (_Float16)((av[j] - (float)h) * 4096.0f);
    }
    #pragma unroll
    for (int nt = 0; nt < 4; ++nt) {
        acc_hh[nt] = __builtin_amdgcn_mfma_f32_16x16x32_f16(ah, bh[nt], acc_hh[nt], 0, 0, 0);
        acc_c[nt]  = __builtin_amdgcn_mfma_f32_16x16x32_f16(ah, bl[nt], acc_c[nt],  0, 0, 0);
        acc_c[nt]  = __builtin_amdgcn_mfma_f32_16x16x32_f16(al, bh[nt], acc_c[nt],  0, 0, 0);
    }
}

__global__ __launch_bounds__(256, 2)
void router_kernel(const float* __restrict__ x,
                   const _Float16* __restrict__ whf,
                   const _Float16* __restrict__ wlf,
                   float* __restrict__ out, int ntok) {
    __shared__ __align__(16) float red[2][64][16];   // khalf=1 partials

    const int tid   = threadIdx.x;
    const int w     = tid >> 6;
    const int l     = tid & 63;
    const int strip = w & 1;
    const int khalf = w >> 1;
    const int tok0  = blockIdx.x * 32;
    const int row   = tok0 + strip * 16 + (l & 15);

    const float* ax = x + (size_t)row * D_MODEL + (l >> 4) * 8;
    const int ksbase = khalf * 64;

    f32x4 acc_hh[4], acc_c[4];
    #pragma unroll
    for (int nt = 0; nt < 4; ++nt) {
        acc_hh[nt] = (f32x4)0.0f;
        acc_c[nt]  = (f32x4)0.0f;
    }

    // depth-2 prefetch ring (statically indexed)
    float4 b0a = *(const float4*)(ax + (size_t)ksbase * 32);
    float4 b0b = *(const float4*)(ax + (size_t)ksbase * 32 + 4);
    float4 b1a = *(const float4*)(ax + (size_t)(ksbase + 1) * 32);
    float4 b1b = *(const float4*)(ax + (size_t)(ksbase + 1) * 32 + 4);

    for (int ks = 0; ks < 64; ks += 2) {
        int kp = ksbase + ks + 2; if (kp > 127) kp = 127;   // clamp: stay in row
        float4 n0 = *(const float4*)(ax + (size_t)kp * 32);
        float4 n1 = *(const float4*)(ax + (size_t)kp * 32 + 4);
        do_kstep(b0a, b0b, whf, wlf, ksbase + ks, l, acc_hh, acc_c);
        b0a = n0; b0b = n1;

        int kq = ksbase + ks + 3; if (kq > 127) kq = 127;
        float4 m0 = *(const float4*)(ax + (size_t)kq * 32);
        float4 m1 = *(const float4*)(ax + (size_t)kq * 32 + 4);
        do_kstep(b1a, b1b, whf, wlf, ksbase + ks + 1, l, acc_hh, acc_c);
        b1a = m0; b1b = m1;
    }

    // per-wave partial logits' (scaled by 2^6): hh + c*2^-12
    f32x4 part[4];
    #pragma unroll
    for (int nt = 0; nt < 4; ++nt)
        part[nt] = acc_hh[nt] + acc_c[nt] * (1.0f / 4096.0f);

    if (khalf == 1) {
        #pragma unroll
        for (int nt = 0; nt < 4; ++nt)
            *(f32x4*)&red[strip][l][nt * 4] = part[nt];
    }
    __syncthreads();
    if (khalf == 1) return;

    // combine K-halves, descale by 2^-6 -> final logits
    float tt[4][4];   // [nt][q]
    #pragma unroll
    for (int nt = 0; nt < 4; ++nt) {
        f32x4 oth = *(const f32x4*)&red[strip][l][nt * 4];
        f32x4 tot = (part[nt] + oth) * (1.0f / 64.0f);
        tt[nt][0] = tot.x; tt[nt][1] = tot.y; tt[nt][2] = tot.z; tt[nt][3] = tot.w;
    }

    float* out_e = out + (size_t)2 * ntok;

    #pragma unroll
    for (int q = 0; q < 4; ++q) {
        // C/D layout (verified m89): col = lane&15, row = (lane>>4)*4 + q
        float v1 = -3.0e38f, v2 = -3.0e38f;
        int   i1 = 1 << 30,  i2 = 1 << 30;
        #pragma unroll
        for (int nt = 0; nt < 4; ++nt) {
            float v  = tt[nt][q];
            int   id = nt * 16 + (l & 15);
            if (v > v1 || (v == v1 && id < i1)) {
                v2 = v1; i2 = i1; v1 = v; i1 = id;
            } else if (v > v2 || (v == v2 && id < i2)) {
                v2 = v; i2 = id;
            }
        }
        // butterfly top-2 merge over the 16-lane group (xor 1,2,4,8)
        #pragma unroll
        for (int m = 1; m < 16; m <<= 1) {
            float ov1 = __shfl_xor(v1, m, 64);
            int   oi1 = __shfl_xor(i1, m, 64);
            float ov2 = __shfl_xor(v2, m, 64);
            int   oi2 = __shfl_xor(i2, m, 64);
            bool ofirst = (ov1 > v1) || (ov1 == v1 && oi1 < i1);
            if (ofirst) {
                bool s2 = (ov2 > v1) || (ov2 == v1 && oi2 < i1);
                v2 = s2 ? ov2 : v1;  i2 = s2 ? oi2 : i1;
                v1 = ov1;            i1 = oi1;
            } else {
                bool s2 = (ov1 > v2) || (ov1 == v2 && oi1 < i2);
                v2 = s2 ? ov1 : v2;  i2 = s2 ? oi1 : i2;
            }
        }

        if ((l & 15) == 0) {
            const int tok = tok0 + strip * 16 + (l >> 4) * 4 + q;
            float e = expf(v2 - v1);     // <= 1
            float d = 1.0f + e;
            out[2 * tok + 0] = 1.0f / d;
            out[2 * tok + 1] = e / d;
            out_e[2 * tok + 0] = (float)i1;
            out_e[2 * tok + 1] = (float)i2;
        }
    }
}

extern "C" void kernel_launch(void* const* d_in, const int* in_sizes, int n_in,
                              void* d_out, int out_size, void* d_ws, size_t ws_size,
                              hipStream_t stream) {
    const float* x = (const float*)d_in[0];
    const float* W = (const float*)d_in[1];
    float* out = (float*)d_out;
    const int ntok = in_sizes[0] / D_MODEL;   // 32768

    _Float16* whf = (_Float16*)d_ws;                          // 512 KB
    _Float16* wlf = (_Float16*)d_ws + (size_t)N_EXP * D_MODEL; // 512 KB

    wprep_kernel<<<dim3(128), dim3(256), 0, stream>>>(W, whf, wlf);
    router_kernel<<<dim3(ntok / 32), dim3(256), 0, stream>>>(x, whf, wlf, out, ntok);
}